// Round 12
// baseline (273.825 us; speedup 1.0000x reference)
//
#include <hip/hip_runtime.h>
#include <hip/hip_bf16.h>

#define BATCH    32768
#define HD       256
#define TM       32
#define NTHREADS 512

#define SCL    2.8853900817779268f   // 2*log2(e): tanh(x) = 1 - 2/(exp2(SCL*x)+1)
#define SCLINV 0.3465735902799726f   // 1/SCL

typedef short  short8 __attribute__((ext_vector_type(8)));
typedef float  f32x16 __attribute__((ext_vector_type(16)));
typedef float  f32x2  __attribute__((ext_vector_type(2)));

// scalar f32 -> bf16 RNE (prepack only)
__device__ __forceinline__ unsigned short f2bf(float f) {
    unsigned u = __float_as_uint(f);
    return (unsigned short)((u + 0x7FFFu + ((u >> 16) & 1u)) >> 16);
}

// packed f32 pair -> bf16x2 (v_cvt_pk_bf16_f32)
__device__ __forceinline__ unsigned pk2(float a, float b) {
    __hip_bfloat162 h = __float22bfloat162_rn(make_float2(a, b));
    return *reinterpret_cast<unsigned*>(&h);
}

// ---- prepack W2^T (scaled by SCL) into bf16 MFMA A-fragment order ----
// A-frag for v_mfma_f32_32x32x16_bf16: lane l holds A[mt*32 + (l&31)][kstep*16 + (l>>5)*8 + i]
// where A = SCL * W2^T. chunk (mt, kstep) at ((mt*16 + kstep)*64 + lane)*8 + i
__global__ void prepack_w2t(const float* __restrict__ W2, unsigned short* __restrict__ wsA) {
    const int k = blockIdx.x;        // K row of W2
    const int j = threadIdx.x;       // output column j (row of W2^T)
    const unsigned short b = f2bf(SCL * W2[k * HD + j]);
    const int kstep = k >> 4, kl = k & 15, hi2 = kl >> 3, i = kl & 7;
    const int mt = j >> 5, jl = j & 31;
    wsA[(((mt * 16) + kstep) * 64 + (hi2 * 32 + jl)) * 8 + i] = b;
}

__global__ __launch_bounds__(NTHREADS, 4)
void cnf1d_rk4_mfma11(const float* __restrict__ z0,
                      const float* __restrict__ W1,
                      const float* __restrict__ b1,
                      const float* __restrict__ b2,
                      const float* __restrict__ W3,
                      const float* __restrict__ b3,
                      const unsigned short* __restrict__ wsA,
                      float* __restrict__ out)
{
    // Staging identical to r8 (conflict-free): 16B slot (granule g = feat/8, row)
    // at uint4 index g*64 + row; rows: U = sample (0..31), T = 32 + sample.
    __shared__ __align__(16) short Abuf[64 * 256];            // 32 KB
    __shared__ float w1zS[HD], w1tS[HD], b1S[HD], w0S[HD];    // 4 KB
    __shared__ float b2sc[HD], w3t[HD];                       // 2 KB
    __shared__ float2 kz[2][8][16];                           // 2 KB  -> 40,960 B

    const int tid  = threadIdx.x;
    const int s0   = blockIdx.x * TM;
    const int lane = tid & 63;
    const int c    = lane & 31;       // MFMA D/B column
    const int hi   = lane >> 5;
    const int wid  = tid >> 6;        // wave: owns j in [wid*32, wid*32+32)
    const int sown = tid & 31;        // owned sample (state/stage/p4)
    const int fb   = tid >> 5;        // staging feature block 0..15
    const bool isT = c >= 16;         // MFMA col is tangent stream
    const int tileOwn = sown >> 4;    // 0 = tile A (s 0..15), 1 = tile B
    const int rowA = c + (isT ? 16 : 0);   // tile-A B-frag row; tile B = +16

    if (tid < HD) {
        const float w0 = W1[tid];
        w1zS[tid] = SCL * w0;
        w1tS[tid] = SCL * W1[HD + tid];
        b1S[tid]  = SCL * b1[tid];
        w0S[tid]  = w0;
        b2sc[tid] = SCL * b2[tid];
        w3t[tid]  = W3[tid];
    }

    // loop-invariant: this wave's W2^T fragments in registers (64 VGPR)
    const short8* __restrict__ wsA8 = (const short8*)wsA;
    short8 w2f[16];
    #pragma unroll
    for (int kk = 0; kk < 16; ++kk)
        w2f[kk] = wsA8[(wid * 16 + kk) * 64 + lane];

    float zbr = z0[s0 + sown];
    float zcr = zbr, skzr = 0.f, skdr = 0.f, daccr = 0.f;
    __syncthreads();

    const float dt  = 0.25f;
    const float b3v = b3[0];
    uint4* __restrict__ Ab4 = (uint4*)Abuf;
    const short8* __restrict__ Ab8 = (const short8*)Abuf;
    const int jbq = wid * 32 + 4 * hi;           // acc-init b2 base
    const f32x2 one2 = {1.f, 1.f};
    const f32x2 m2   = {-2.f, -2.f};

    auto te_of = [&](int n) -> float {
        const int e = n & 3;
        return (n >> 2) * dt + ((e == 0) ? 0.f : (e == 3) ? dt : 0.5f * dt);
    };

    // stage this thread's sample (16 features), r8 body verbatim
    auto stage_own = [&](float te) {
        const f32x2 zc2 = {zcr, zcr};
        const f32x2 te2 = {te, te};
        #pragma unroll
        for (int g2 = 0; g2 < 2; ++g2) {
            const int j0 = fb * 16 + g2 * 8;
            const float4 wzA = *(const float4*)&w1zS[j0];
            const float4 wzB = *(const float4*)&w1zS[j0 + 4];
            const float4 wtA = *(const float4*)&w1tS[j0];
            const float4 wtB = *(const float4*)&w1tS[j0 + 4];
            const float4 bbA = *(const float4*)&b1S[j0];
            const float4 bbB = *(const float4*)&b1S[j0 + 4];
            const float4 w0A = *(const float4*)&w0S[j0];
            const float4 w0B = *(const float4*)&w0S[j0 + 4];
            const f32x2 wz[4]  = {{wzA.x, wzA.y}, {wzA.z, wzA.w}, {wzB.x, wzB.y}, {wzB.z, wzB.w}};
            const f32x2 wt[4]  = {{wtA.x, wtA.y}, {wtA.z, wtA.w}, {wtB.x, wtB.y}, {wtB.z, wtB.w}};
            const f32x2 bb[4]  = {{bbA.x, bbA.y}, {bbA.z, bbA.w}, {bbB.x, bbB.y}, {bbB.z, bbB.w}};
            const f32x2 w0p[4] = {{w0A.x, w0A.y}, {w0A.z, w0A.w}, {w0B.x, w0B.y}, {w0B.z, w0B.w}};
            f32x2 hh[4], th[4];
            #pragma unroll
            for (int pp = 0; pp < 4; ++pp) {
                const f32x2 a = __builtin_elementwise_fma(zc2, wz[pp],
                                  __builtin_elementwise_fma(te2, wt[pp], bb[pp]));
                f32x2 ev; ev.x = __builtin_amdgcn_exp2f(a.x);
                          ev.y = __builtin_amdgcn_exp2f(a.y);
                const f32x2 e1 = ev + one2;
                f32x2 rv; rv.x = __builtin_amdgcn_rcpf(e1.x);
                          rv.y = __builtin_amdgcn_rcpf(e1.y);
                const f32x2 h  = __builtin_elementwise_fma(m2, rv, one2);
                const f32x2 t1 = __builtin_elementwise_fma(-h, h, one2);
                hh[pp] = h;
                th[pp] = t1 * w0p[pp];
            }
            uint4 vU, vT;
            vU.x = pk2(hh[0].x, hh[0].y);  vU.y = pk2(hh[1].x, hh[1].y);
            vU.z = pk2(hh[2].x, hh[2].y);  vU.w = pk2(hh[3].x, hh[3].y);
            vT.x = pk2(th[0].x, th[0].y);  vT.y = pk2(th[1].x, th[1].y);
            vT.z = pk2(th[2].x, th[2].y);  vT.w = pk2(th[3].x, th[3].y);
            const int gr = j0 >> 3;
            Ab4[gr * 64 + sown]      = vU;   // U row
            Ab4[gr * 64 + 32 + sown] = vT;   // T row
        }
    };

    // RK4 update for this thread's sample from kz[tileOwn]
    auto p4 = [&](int n) {
        float k_z = b3v, k_d = 0.f;
        #pragma unroll
        for (int w = 0; w < 8; ++w) {
            const float2 a = kz[tileOwn][w][sown & 15];
            k_z += a.x; k_d += a.y;
        }
        const int e = n & 3;
        const float cw = (e == 1 || e == 2) ? 2.f : 1.f;
        skzr += cw * k_z;
        skdr += cw * k_d;
        if (e < 3) {
            zcr = fmaf((e == 2) ? dt : 0.5f * dt, k_z, zbr);
        } else {
            zbr   = fmaf(dt / 6.f, skzr, zbr);
            zcr   = zbr;
            daccr = fmaf(dt / 6.f, skdr, daccr);
            skzr = 0.f; skdr = 0.f;
        }
    };

    // epilogue for tile X: pair U/T via shfl_xor(16), static row split
    auto epi = [&](int X, const f32x16& acc) {
        const int bw3 = jbq + (isT ? 16 : 0);
        const float4 w3a = *(const float4*)&w3t[bw3];
        const float4 w3b = *(const float4*)&w3t[bw3 + 8];
        float pdz = 0.f, pdd = 0.f;
        #pragma unroll
        for (int q = 0; q < 8; ++q) {
            const float swLo = __shfl_xor(acc[q], 16);
            const float swHi = __shfl_xor(acc[8 + q], 16);
            const float u = isT ? swHi : acc[q];          // U value for this lane's row
            const float t = isT ? acc[8 + q] : swLo;      // matching SCL*tu
            const float ev = __builtin_amdgcn_exp2f(u);
            const float r1 = __builtin_amdgcn_rcpf(ev + 1.f);
            const float h2 = fmaf(-2.f, r1, 1.f);
            const float th2 = fmaf(-h2 * h2, t, t);
            const float w3c = (q < 4) ? ((const float*)&w3a)[q] : ((const float*)&w3b)[q - 4];
            pdz = fmaf(h2,  w3c, pdz);
            pdd = fmaf(th2, w3c, pdd);
        }
        pdd *= SCLINV;
        pdz += __shfl_xor(pdz, 16);  pdd += __shfl_xor(pdd, 16);
        pdz += __shfl_xor(pdz, 32);  pdd += __shfl_xor(pdd, 32);
        if (!isT && hi == 0) kz[X][wid][c] = make_float2(pdz, pdd);
    };

    // ---- prologue: stage tile A for eval 0 ----
    if (tileOwn == 0) stage_own(te_of(0));
    __syncthreads();

    for (int it = 0; it < 16; ++it) {
        // R1: MFMA(A,it) || { p4(B,it-1), stage(B,it) } ; epi(A)
        {
            f32x16 acc;
            #pragma unroll
            for (int rq = 0; rq < 4; ++rq) {
                const float4 bq = *(const float4*)&b2sc[jbq + rq * 8];
                acc[rq * 4 + 0] = isT ? 0.f : bq.x;
                acc[rq * 4 + 1] = isT ? 0.f : bq.y;
                acc[rq * 4 + 2] = isT ? 0.f : bq.z;
                acc[rq * 4 + 3] = isT ? 0.f : bq.w;
            }
            #pragma unroll
            for (int kk = 0; kk < 16; ++kk) {
                const short8 hB = Ab8[(kk * 2 + hi) * 64 + rowA];
                acc = __builtin_amdgcn_mfma_f32_32x32x16_bf16(w2f[kk], hB, acc, 0, 0, 0);
            }
            if (tileOwn == 1) {                 // independent VALU under MFMA shadow
                if (it > 0) p4(it - 1);
                stage_own(te_of(it));
            }
            epi(0, acc);
        }
        __syncthreads();

        // R2: MFMA(B,it) || { p4(A,it), stage(A,it+1) } ; epi(B)
        {
            f32x16 acc;
            #pragma unroll
            for (int rq = 0; rq < 4; ++rq) {
                const float4 bq = *(const float4*)&b2sc[jbq + rq * 8];
                acc[rq * 4 + 0] = isT ? 0.f : bq.x;
                acc[rq * 4 + 1] = isT ? 0.f : bq.y;
                acc[rq * 4 + 2] = isT ? 0.f : bq.z;
                acc[rq * 4 + 3] = isT ? 0.f : bq.w;
            }
            #pragma unroll
            for (int kk = 0; kk < 16; ++kk) {
                const short8 hB = Ab8[(kk * 2 + hi) * 64 + rowA + 16];
                acc = __builtin_amdgcn_mfma_f32_32x32x16_bf16(w2f[kk], hB, acc, 0, 0, 0);
            }
            if (tileOwn == 0) {
                p4(it);
                if (it < 15) stage_own(te_of(it + 1));
            }
            epi(1, acc);
        }
        __syncthreads();
    }
    if (tileOwn == 1) p4(15);       // final tile-B RK4 update

    if (tid < TM) {
        out[s0 + tid]         = zbr;     // zf
        out[BATCH + s0 + tid] = daccr;   // div_int
    }
}

extern "C" void kernel_launch(void* const* d_in, const int* in_sizes, int n_in,
                              void* d_out, int out_size, void* d_ws, size_t ws_size,
                              hipStream_t stream) {
    const float* z0 = (const float*)d_in[0];
    const float* W1 = (const float*)d_in[1];
    const float* b1 = (const float*)d_in[2];
    const float* W2 = (const float*)d_in[3];
    const float* b2 = (const float*)d_in[4];
    const float* W3 = (const float*)d_in[5];
    const float* b3 = (const float*)d_in[6];
    float* out = (float*)d_out;
    unsigned short* wsA = (unsigned short*)d_ws;   // 128 KB bf16 A-frag SCL*W2^T

    hipLaunchKernelGGL(prepack_w2t, dim3(HD), dim3(HD), 0, stream, W2, wsA);
    hipLaunchKernelGGL(cnf1d_rk4_mfma11, dim3(BATCH / TM), dim3(NTHREADS), 0, stream,
                       z0, W1, b1, b2, W3, b3, wsA, out);
}

// Round 13
// 258.270 us; speedup vs baseline: 1.0602x; 1.0602x over previous
//
#include <hip/hip_runtime.h>
#include <hip/hip_bf16.h>

#define BATCH    32768
#define HD       256
#define TM       32
#define NTHREADS 512

#define SCL    2.8853900817779268f   // 2*log2(e): tanh(x) = 1 - 2/(exp2(SCL*x)+1)
#define SCLINV 0.3465735902799726f   // 1/SCL

typedef short  short8 __attribute__((ext_vector_type(8)));
typedef float  f32x16 __attribute__((ext_vector_type(16)));
typedef float  f32x2  __attribute__((ext_vector_type(2)));

__device__ __forceinline__ unsigned short f2bf(float f) {
    unsigned u = __float_as_uint(f);
    return (unsigned short)((u + 0x7FFFu + ((u >> 16) & 1u)) >> 16);
}

__device__ __forceinline__ unsigned pk2(float a, float b) {
    __hip_bfloat162 h = __float22bfloat162_rn(make_float2(a, b));
    return *reinterpret_cast<unsigned*>(&h);
}

// prepack SCL*W2^T into bf16 A-frag order for v_mfma_f32_32x32x16_bf16 (as before)
__global__ void prepack_w2t(const float* __restrict__ W2, unsigned short* __restrict__ wsA) {
    const int k = blockIdx.x;
    const int j = threadIdx.x;
    const unsigned short b = f2bf(SCL * W2[k * HD + j]);
    const int kstep = k >> 4, kl = k & 15, hi2 = kl >> 3, i = kl & 7;
    const int mt = j >> 5, jl = j & 31;
    wsA[(((mt * 16) + kstep) * 64 + (hi2 * 32 + jl)) * 8 + i] = b;
}

__global__ __launch_bounds__(NTHREADS, 4)
void cnf1d_rk4_mfma12(const float* __restrict__ z0,
                      const float* __restrict__ W1,
                      const float* __restrict__ b1,
                      const float* __restrict__ b2,
                      const float* __restrict__ W3,
                      const float* __restrict__ b3,
                      const unsigned short* __restrict__ wsA,
                      float* __restrict__ out)
{
    // staging: 16B slot (granule g = feat/8, row); rows: U = 16*X + s, T = 32 + 16*X + s
    __shared__ __align__(16) short Abuf[64 * 256];            // 32 KB
    __shared__ float w1zS[HD], w1tS[HD], b1S[HD], w0S[HD];    // 4 KB
    __shared__ float b2sc[HD], w3t[HD];                       // 2 KB
    __shared__ float2 kz[2][8][16];                           // 2 KB -> 40,960 B

    const int tid  = threadIdx.x;
    const int s0   = blockIdx.x * TM;
    const int lane = tid & 63;
    const int c    = lane & 31;
    const int hi   = lane >> 5;
    const int wid  = tid >> 6;
    const int sloc = tid & 15;        // staging/p4 sample within tile
    const int fq   = tid >> 4;        // staging granule 0..31 (8 feats)
    const bool isT = c >= 16;
    const int rowU = c + (isT ? 16 : 0);   // tile-A B-frag row; tile B adds +16
    const int jbq  = wid * 32 + 4 * hi;

    if (tid < HD) {
        const float w0 = W1[tid];
        w1zS[tid] = SCL * w0;
        w1tS[tid] = SCL * W1[HD + tid];
        b1S[tid]  = SCL * b1[tid];
        w0S[tid]  = w0;
        b2sc[tid] = SCL * b2[tid];
        w3t[tid]  = W3[tid];
    }

    const short8* __restrict__ wsA8 = (const short8*)wsA;
    short8 w2f[16];
    #pragma unroll
    for (int kk = 0; kk < 16; ++kk)
        w2f[kk] = wsA8[(wid * 16 + kk) * 64 + lane];

    // both tiles' RK4 state in every thread (sample sloc of each tile)
    float zbA = z0[s0 + sloc],      zcA = zbA, skzA = 0.f, skdA = 0.f, daccA = 0.f;
    float zbB = z0[s0 + 16 + sloc], zcB = zbB, skzB = 0.f, skdB = 0.f, daccB = 0.f;

    const float dt  = 0.25f;
    const float b3v = b3[0];
    uint4* __restrict__ Ab4 = (uint4*)Abuf;
    const short8* __restrict__ Ab8 = (const short8*)Abuf;
    const f32x2 one2 = {1.f, 1.f};
    const f32x2 m2   = {-2.f, -2.f};
    __syncthreads();

    // loop-invariant per-lane W3 values (8 regs)
    float w3r[8];
    #pragma unroll
    for (int q = 0; q < 8; ++q)
        w3r[q] = w3t[wid * 32 + 4 * hi + (isT ? 16 : 0) + ((q < 4) ? q : q + 4)];

    auto te_of = [&](int n) -> float {
        const int e = n & 3;
        return (n >> 2) * dt + ((e == 0) ? 0.f : (e == 3) ? dt : 0.5f * dt);
    };

    // all threads stage tile X: 8 features (granule fq) of sample sloc
    auto stage = [&](int X, float zc, float te) {
        const f32x2 zc2 = {zc, zc};
        const f32x2 te2 = {te, te};
        const int j0 = fq * 8;
        unsigned uw0, uw1, uw2, uw3, tw0, tw1, tw2, tw3;
        #pragma unroll
        for (int pp = 0; pp < 4; ++pp) {
            const f32x2 wz = *(const f32x2*)&w1zS[j0 + 2 * pp];
            const f32x2 wt = *(const f32x2*)&w1tS[j0 + 2 * pp];
            const f32x2 bb = *(const f32x2*)&b1S[j0 + 2 * pp];
            const f32x2 w0 = *(const f32x2*)&w0S[j0 + 2 * pp];
            const f32x2 a  = __builtin_elementwise_fma(zc2, wz,
                               __builtin_elementwise_fma(te2, wt, bb));
            f32x2 ev; ev.x = __builtin_amdgcn_exp2f(a.x);
                      ev.y = __builtin_amdgcn_exp2f(a.y);
            const f32x2 e1 = ev + one2;
            f32x2 rv; rv.x = __builtin_amdgcn_rcpf(e1.x);
                      rv.y = __builtin_amdgcn_rcpf(e1.y);
            const f32x2 h  = __builtin_elementwise_fma(m2, rv, one2);
            const f32x2 t1 = __builtin_elementwise_fma(-h, h, one2);
            const f32x2 th = t1 * w0;
            const unsigned hu = pk2(h.x, h.y);
            const unsigned tu = pk2(th.x, th.y);
            if (pp == 0) { uw0 = hu; tw0 = tu; }
            else if (pp == 1) { uw1 = hu; tw1 = tu; }
            else if (pp == 2) { uw2 = hu; tw2 = tu; }
            else { uw3 = hu; tw3 = tu; }
        }
        uint4 vU = {uw0, uw1, uw2, uw3};
        uint4 vT = {tw0, tw1, tw2, tw3};
        Ab4[fq * 64 + 16 * X + sloc]      = vU;
        Ab4[fq * 64 + 32 + 16 * X + sloc] = vT;
    };

    auto p4 = [&](int X, int n, float& zb, float& zc, float& skz, float& skd, float& dacc) {
        float k_z = b3v, k_d = 0.f;
        #pragma unroll
        for (int w = 0; w < 8; ++w) {
            const float2 a = kz[X][w][sloc];
            k_z += a.x; k_d += a.y;
        }
        const int e = n & 3;
        const float cw = (e == 1 || e == 2) ? 2.f : 1.f;
        skz += cw * k_z;
        skd += cw * k_d;
        if (e < 3) {
            zc = fmaf((e == 2) ? dt : 0.5f * dt, k_z, zb);
        } else {
            zb   = fmaf(dt / 6.f, skz, zb);
            zc   = zb;
            dacc = fmaf(dt / 6.f, skd, dacc);
            skz = 0.f; skd = 0.f;
        }
    };

    // prologue: stage tile A for eval 0
    stage(0, zcA, te_of(0));
    __syncthreads();

    for (int it = 0; it < 16; ++it) {
        // ---------------- R1: MFMA(A,it) || { p4(B,it-1); stage(B,it) } ; epi(A) ----
        {
            f32x16 acc;
            #pragma unroll
            for (int rq = 0; rq < 4; ++rq) {
                const float4 bq = *(const float4*)&b2sc[jbq + rq * 8];
                acc[rq * 4 + 0] = isT ? 0.f : bq.x;
                acc[rq * 4 + 1] = isT ? 0.f : bq.y;
                acc[rq * 4 + 2] = isT ? 0.f : bq.z;
                acc[rq * 4 + 3] = isT ? 0.f : bq.w;
            }
            #pragma unroll
            for (int kk = 0; kk < 16; ++kk) {
                const short8 hB = Ab8[(kk * 2 + hi) * 64 + rowU];
                acc = __builtin_amdgcn_mfma_f32_32x32x16_bf16(w2f[kk], hB, acc, 0, 0, 0);
            }
            if (it > 0) p4(1, it - 1, zbB, zcB, skzB, skdB, daccB);
            stage(1, zcB, te_of(it));
            // epilogue A
            float pdz = 0.f, pdd = 0.f;
            #pragma unroll
            for (int q = 0; q < 8; ++q) {
                const float swLo = __shfl_xor(acc[q], 16);
                const float swHi = __shfl_xor(acc[8 + q], 16);
                const float u = isT ? swHi : acc[q];
                const float t = isT ? acc[8 + q] : swLo;
                const float ev = __builtin_amdgcn_exp2f(u);
                const float r1 = __builtin_amdgcn_rcpf(ev + 1.f);
                const float h2 = fmaf(-2.f, r1, 1.f);
                const float th2 = fmaf(-h2 * h2, t, t);
                pdz = fmaf(h2,  w3r[q], pdz);
                pdd = fmaf(th2, w3r[q], pdd);
            }
            pdd *= SCLINV;
            pdz += __shfl_xor(pdz, 16);  pdd += __shfl_xor(pdd, 16);
            pdz += __shfl_xor(pdz, 32);  pdd += __shfl_xor(pdd, 32);
            if (!isT && hi == 0) kz[0][wid][c] = make_float2(pdz, pdd);
        }
        __syncthreads();

        // ---------------- R2: MFMA(B,it) || { p4(A,it); stage(A,it+1) } ; epi(B) ----
        {
            f32x16 acc;
            #pragma unroll
            for (int rq = 0; rq < 4; ++rq) {
                const float4 bq = *(const float4*)&b2sc[jbq + rq * 8];
                acc[rq * 4 + 0] = isT ? 0.f : bq.x;
                acc[rq * 4 + 1] = isT ? 0.f : bq.y;
                acc[rq * 4 + 2] = isT ? 0.f : bq.z;
                acc[rq * 4 + 3] = isT ? 0.f : bq.w;
            }
            #pragma unroll
            for (int kk = 0; kk < 16; ++kk) {
                const short8 hB = Ab8[(kk * 2 + hi) * 64 + rowU + 16];
                acc = __builtin_amdgcn_mfma_f32_32x32x16_bf16(w2f[kk], hB, acc, 0, 0, 0);
            }
            p4(0, it, zbA, zcA, skzA, skdA, daccA);
            if (it < 15) stage(0, zcA, te_of(it + 1));
            // epilogue B
            float pdz = 0.f, pdd = 0.f;
            #pragma unroll
            for (int q = 0; q < 8; ++q) {
                const float swLo = __shfl_xor(acc[q], 16);
                const float swHi = __shfl_xor(acc[8 + q], 16);
                const float u = isT ? swHi : acc[q];
                const float t = isT ? acc[8 + q] : swLo;
                const float ev = __builtin_amdgcn_exp2f(u);
                const float r1 = __builtin_amdgcn_rcpf(ev + 1.f);
                const float h2 = fmaf(-2.f, r1, 1.f);
                const float th2 = fmaf(-h2 * h2, t, t);
                pdz = fmaf(h2,  w3r[q], pdz);
                pdd = fmaf(th2, w3r[q], pdd);
            }
            pdd *= SCLINV;
            pdz += __shfl_xor(pdz, 16);  pdd += __shfl_xor(pdd, 16);
            pdz += __shfl_xor(pdz, 32);  pdd += __shfl_xor(pdd, 32);
            if (!isT && hi == 0) kz[1][wid][c] = make_float2(pdz, pdd);
        }
        __syncthreads();
    }
    p4(1, 15, zbB, zcB, skzB, skdB, daccB);   // final tile-B update

    if (tid < TM) {
        const bool tB = tid >= 16;
        out[s0 + tid]         = tB ? zbB   : zbA;
        out[BATCH + s0 + tid] = tB ? daccB : daccA;
    }
}

extern "C" void kernel_launch(void* const* d_in, const int* in_sizes, int n_in,
                              void* d_out, int out_size, void* d_ws, size_t ws_size,
                              hipStream_t stream) {
    const float* z0 = (const float*)d_in[0];
    const float* W1 = (const float*)d_in[1];
    const float* b1 = (const float*)d_in[2];
    const float* W2 = (const float*)d_in[3];
    const float* b2 = (const float*)d_in[4];
    const float* W3 = (const float*)d_in[5];
    const float* b3 = (const float*)d_in[6];
    float* out = (float*)d_out;
    unsigned short* wsA = (unsigned short*)d_ws;   // 128 KB bf16 A-frag SCL*W2^T

    hipLaunchKernelGGL(prepack_w2t, dim3(HD), dim3(HD), 0, stream, W2, wsA);
    hipLaunchKernelGGL(cnf1d_rk4_mfma12, dim3(BATCH / TM), dim3(NTHREADS), 0, stream,
                       z0, W1, b1, b2, W3, b3, wsA, out);
}

// Round 14
// 47.382 us; speedup vs baseline: 5.7791x; 5.4508x over previous
//
#include <hip/hip_runtime.h>
#include <hip/hip_bf16.h>

#define BATCH    32768
#define HD       256
#define G        1600          // z-grid points per te slice
#define NTE      9             // distinct te values: 0, 0.125, ..., 1.0
#define ZMIN     -20.0f
#define HSTEP    0.025f        // 40/G
#define INVH     40.0f         // G/40

#define SCL    2.8853900817779268f   // 2*log2(e): tanh(x) = 1 - 2/(exp2(SCL*x)+1)
#define SCLINV 0.3465735902799726f   // 1/SCL

typedef short  short8 __attribute__((ext_vector_type(8)));
typedef float  f32x16 __attribute__((ext_vector_type(16)));
typedef float  f32x2  __attribute__((ext_vector_type(2)));

// packed f32 pair -> bf16x2 (v_cvt_pk_bf16_f32)
__device__ __forceinline__ unsigned pk2(float a, float b) {
    __hip_bfloat162 h = __float22bfloat162_rn(make_float2(a, b));
    return *reinterpret_cast<unsigned*>(&h);
}

// ---- kernel 1: tabulate dz = f(te, z) and dd = df/dz(te, z) on the z-grid ----
// 450 blocks = 9 te x 50 chunks of 32 grid points; 512 threads; r8 MFMA engine.
__global__ __launch_bounds__(512, 4)
void build_table(const float* __restrict__ W1,
                 const float* __restrict__ b1,
                 const float* __restrict__ W2,
                 const float* __restrict__ b2,
                 const float* __restrict__ W3,
                 const float* __restrict__ b3,
                 float2* __restrict__ tbl)
{
    // staging: 16B slot (granule g = feat/8, row); rows 0..31 = h1, 32..63 = th1
    __shared__ __align__(16) short Abuf[64 * 256];            // 32 KB
    __shared__ float w1zS[HD], w1tS[HD], b1S[HD], w0S[HD];    // 4 KB
    __shared__ float b2sc[HD], w3t[HD];                       // 2 KB
    __shared__ float2 kz[8][32];                              // 2 KB -> 40,960 B

    const int tid  = threadIdx.x;
    const int lane = tid & 63;
    const int c    = lane & 31;
    const int hi   = lane >> 5;
    const int wid  = tid >> 6;        // wave: j in [wid*32, wid*32+32)
    const int s    = tid & 31;        // grid point within chunk
    const int fb   = tid >> 5;        // staging feature block 0..15
    const int teI  = blockIdx.x / (G / 32);
    const int zblk = blockIdx.x % (G / 32);

    const float te = teI * 0.125f;
    const float zv = ZMIN + (float)(zblk * 32 + s) * HSTEP;

    if (tid < HD) {
        const float w0 = W1[tid];
        w1zS[tid] = SCL * w0;
        w1tS[tid] = SCL * W1[HD + tid];
        b1S[tid]  = SCL * b1[tid];
        w0S[tid]  = w0;
        b2sc[tid] = SCL * b2[tid];
        w3t[tid]  = W3[tid];
    }
    const float b3v = b3[0];

    // stream this wave's W2^T fragments straight from global (L2-resident),
    // converting to SCL-scaled bf16 A-frag order on the fly (r8 layout).
    short8 w2f[16];
    #pragma unroll
    for (int kk = 0; kk < 16; ++kk) {
        float v[8];
        #pragma unroll
        for (int i = 0; i < 8; ++i) {
            const int k = kk * 16 + hi * 8 + i;
            v[i] = SCL * W2[k * HD + wid * 32 + c];
        }
        union { short8 s8; uint4 u4; } w;
        w.u4.x = pk2(v[0], v[1]);  w.u4.y = pk2(v[2], v[3]);
        w.u4.z = pk2(v[4], v[5]);  w.u4.w = pk2(v[6], v[7]);
        w2f[kk] = w.s8;
    }
    __syncthreads();

    const f32x2 one2 = {1.f, 1.f};
    const f32x2 m2   = {-2.f, -2.f};
    uint4* __restrict__ Ab4 = (uint4*)Abuf;
    const short8* __restrict__ Ab8 = (const short8*)Abuf;
    const int jb = wid * 32 + hi * 4;

    // ---- phase 1: h1/th1 for this block's 32 grid points (r8 verbatim) ----
    {
        const f32x2 zc2 = {zv, zv};
        const f32x2 te2 = {te, te};
        #pragma unroll
        for (int g2 = 0; g2 < 2; ++g2) {
            const int j0 = fb * 16 + g2 * 8;
            const float4 wzA = *(const float4*)&w1zS[j0];
            const float4 wzB = *(const float4*)&w1zS[j0 + 4];
            const float4 wtA = *(const float4*)&w1tS[j0];
            const float4 wtB = *(const float4*)&w1tS[j0 + 4];
            const float4 bbA = *(const float4*)&b1S[j0];
            const float4 bbB = *(const float4*)&b1S[j0 + 4];
            const float4 w0A = *(const float4*)&w0S[j0];
            const float4 w0B = *(const float4*)&w0S[j0 + 4];
            const f32x2 wz[4]  = {{wzA.x, wzA.y}, {wzA.z, wzA.w}, {wzB.x, wzB.y}, {wzB.z, wzB.w}};
            const f32x2 wt[4]  = {{wtA.x, wtA.y}, {wtA.z, wtA.w}, {wtB.x, wtB.y}, {wtB.z, wtB.w}};
            const f32x2 bb[4]  = {{bbA.x, bbA.y}, {bbA.z, bbA.w}, {bbB.x, bbB.y}, {bbB.z, bbB.w}};
            const f32x2 w0p[4] = {{w0A.x, w0A.y}, {w0A.z, w0A.w}, {w0B.x, w0B.y}, {w0B.z, w0B.w}};
            f32x2 hh[4], th[4];
            #pragma unroll
            for (int pp = 0; pp < 4; ++pp) {
                const f32x2 a = __builtin_elementwise_fma(zc2, wz[pp],
                                  __builtin_elementwise_fma(te2, wt[pp], bb[pp]));
                f32x2 ev; ev.x = __builtin_amdgcn_exp2f(a.x);
                          ev.y = __builtin_amdgcn_exp2f(a.y);
                const f32x2 e1 = ev + one2;
                f32x2 rv; rv.x = __builtin_amdgcn_rcpf(e1.x);
                          rv.y = __builtin_amdgcn_rcpf(e1.y);
                const f32x2 h  = __builtin_elementwise_fma(m2, rv, one2);   // tanh
                const f32x2 t1 = __builtin_elementwise_fma(-h, h, one2);    // 1 - h^2
                hh[pp] = h;
                th[pp] = t1 * w0p[pp];
            }
            uint4 vU, vT;
            vU.x = pk2(hh[0].x, hh[0].y);  vU.y = pk2(hh[1].x, hh[1].y);
            vU.z = pk2(hh[2].x, hh[2].y);  vU.w = pk2(hh[3].x, hh[3].y);
            vT.x = pk2(th[0].x, th[0].y);  vT.y = pk2(th[1].x, th[1].y);
            vT.z = pk2(th[2].x, th[2].y);  vT.w = pk2(th[3].x, th[3].y);
            const int gr = j0 >> 3;
            Ab4[gr * 64 + s]      = vU;
            Ab4[gr * 64 + 32 + s] = vT;
        }
    }
    __syncthreads();

    // ---- phase 2: MFMA (r8 verbatim) ----
    f32x16 accU, accT;
    #pragma unroll
    for (int rq = 0; rq < 4; ++rq) {
        const float4 bq = *(const float4*)&b2sc[jb + rq * 8];
        accU[rq * 4 + 0] = bq.x;  accU[rq * 4 + 1] = bq.y;
        accU[rq * 4 + 2] = bq.z;  accU[rq * 4 + 3] = bq.w;
        accT[rq * 4 + 0] = 0.f;   accT[rq * 4 + 1] = 0.f;
        accT[rq * 4 + 2] = 0.f;   accT[rq * 4 + 3] = 0.f;
    }
    #pragma unroll
    for (int kk = 0; kk < 16; ++kk) {
        const short8 hU = Ab8[(kk * 2 + hi) * 64 + c];
        const short8 hT = Ab8[(kk * 2 + hi) * 64 + 32 + c];
        accU = __builtin_amdgcn_mfma_f32_32x32x16_bf16(w2f[kk], hU, accU, 0, 0, 0);
        accT = __builtin_amdgcn_mfma_f32_32x32x16_bf16(w2f[kk], hT, accT, 0, 0, 0);
    }

    // ---- phase 3: epilogue (r8 verbatim) ----
    f32x2 pz2 = {0.f, 0.f}, pd2 = {0.f, 0.f};
    #pragma unroll
    for (int rq = 0; rq < 4; ++rq) {
        const float4 w3q = *(const float4*)&w3t[jb + rq * 8];
        const f32x2 w3p[2] = {{w3q.x, w3q.y}, {w3q.z, w3q.w}};
        #pragma unroll
        for (int pr = 0; pr < 2; ++pr) {
            const int r = rq * 4 + pr * 2;
            const f32x2 u2 = {accU[r], accU[r + 1]};
            const f32x2 t2 = {accT[r], accT[r + 1]};
            f32x2 ev; ev.x = __builtin_amdgcn_exp2f(u2.x);
                      ev.y = __builtin_amdgcn_exp2f(u2.y);
            const f32x2 e1 = ev + one2;
            f32x2 rv; rv.x = __builtin_amdgcn_rcpf(e1.x);
                      rv.y = __builtin_amdgcn_rcpf(e1.y);
            const f32x2 h2 = __builtin_elementwise_fma(m2, rv, one2);
            const f32x2 hq = h2 * h2;
            const f32x2 th2 = __builtin_elementwise_fma(-hq, t2, t2);
            pz2 = __builtin_elementwise_fma(h2,  w3p[pr], pz2);
            pd2 = __builtin_elementwise_fma(th2, w3p[pr], pd2);
        }
    }
    float pdz = pz2.x + pz2.y;
    float pdd = (pd2.x + pd2.y) * SCLINV;
    pdz += __shfl_xor(pdz, 32);
    pdd += __shfl_xor(pdd, 32);
    if (hi == 0) kz[wid][c] = make_float2(pdz, pdd);
    __syncthreads();

    // ---- reduce the 8 wave-partials and store table entry ----
    if (tid < 32) {
        float kzs = b3v, kds = 0.f;
        #pragma unroll
        for (int w = 0; w < 8; ++w) {
            const float2 a = kz[w][tid];
            kzs += a.x; kds += a.y;
        }
        tbl[teI * G + zblk * 32 + tid] = make_float2(kzs, kds);
    }
}

// ---- kernel 2: RK4 integration of all samples via table interpolation ----
__global__ __launch_bounds__(128)
void integrate(const float* __restrict__ z0,
               const float2* __restrict__ tbl,
               float* __restrict__ out)
{
    __shared__ float2 sl[G];                 // 12.8 KB: current te slice
    const int tid = threadIdx.x;
    const int sid = blockIdx.x * 128 + tid;

    float zb = z0[sid];
    float zc = zb, skz = 0.f, skd = 0.f, dacc = 0.f;
    const float dt = 0.25f;
    int prev = -1;

    for (int it = 0; it < 16; ++it) {
        const int st = it >> 2, e = it & 3;
        const int idx = 2 * st + ((e == 0) ? 0 : (e == 3) ? 2 : 1);
        if (idx != prev) {                    // block-uniform condition
            __syncthreads();                  // prior interp done before overwrite
            for (int g = tid; g < G; g += 128)
                sl[g] = tbl[idx * G + g];
            __syncthreads();
            prev = idx;
        }
        float xf = (zc - ZMIN) * INVH;
        xf = fminf(fmaxf(xf, 0.0f), (float)(G - 1));
        int i0 = (int)xf;
        if (i0 > G - 2) i0 = G - 2;
        const float w  = xf - (float)i0;
        const float2 a = sl[i0];
        const float2 b = sl[i0 + 1];
        const float kzv = fmaf(w, b.x - a.x, a.x);
        const float kdv = fmaf(w, b.y - a.y, a.y);

        const float cw = (e == 1 || e == 2) ? 2.f : 1.f;
        skz += cw * kzv;
        skd += cw * kdv;
        if (e < 3) {
            zc = fmaf((e == 2) ? dt : 0.5f * dt, kzv, zb);
        } else {
            zb   = fmaf(dt / 6.f, skz, zb);
            zc   = zb;
            dacc = fmaf(dt / 6.f, skd, dacc);
            skz = 0.f; skd = 0.f;
        }
    }

    out[sid]         = zb;      // zf
    out[BATCH + sid] = dacc;    // div_int
}

extern "C" void kernel_launch(void* const* d_in, const int* in_sizes, int n_in,
                              void* d_out, int out_size, void* d_ws, size_t ws_size,
                              hipStream_t stream) {
    const float* z0 = (const float*)d_in[0];
    const float* W1 = (const float*)d_in[1];
    const float* b1 = (const float*)d_in[2];
    const float* W2 = (const float*)d_in[3];
    const float* b2 = (const float*)d_in[4];
    const float* W3 = (const float*)d_in[5];
    const float* b3 = (const float*)d_in[6];
    float* out = (float*)d_out;
    float2* tbl = (float2*)d_ws;   // 9 * 1600 * 8 B = 115,200 B (< proven 128 KB)

    hipLaunchKernelGGL(build_table, dim3(NTE * (G / 32)), dim3(512), 0, stream,
                       W1, b1, W2, b2, W3, b3, tbl);
    hipLaunchKernelGGL(integrate, dim3(BATCH / 128), dim3(128), 0, stream,
                       z0, tbl, out);
}

// Round 15
// 35.075 us; speedup vs baseline: 7.8067x; 1.3509x over previous
//
#include <hip/hip_runtime.h>
#include <hip/hip_bf16.h>

#define BATCH    32768
#define HD       256
#define G        1600          // z-grid points per te slice
#define NTE      9             // distinct te values: 0, 0.125, ..., 1.0
#define ZMIN     -20.0f
#define HSTEP    0.025f        // 40/G
#define INVH     40.0f         // G/40

#define SCL    2.8853900817779268f   // 2*log2(e): tanh(x) = 1 - 2/(exp2(SCL*x)+1)
#define SCLINV 0.3465735902799726f   // 1/SCL

typedef short  short8 __attribute__((ext_vector_type(8)));
typedef float  f32x16 __attribute__((ext_vector_type(16)));
typedef float  f32x2  __attribute__((ext_vector_type(2)));

// scalar f32 -> bf16 RNE (prepack)
__device__ __forceinline__ unsigned short f2bf(float f) {
    unsigned u = __float_as_uint(f);
    return (unsigned short)((u + 0x7FFFu + ((u >> 16) & 1u)) >> 16);
}

// packed f32 pair -> bf16x2 (v_cvt_pk_bf16_f32)
__device__ __forceinline__ unsigned pk2(float a, float b) {
    __hip_bfloat162 h = __float22bfloat162_rn(make_float2(a, b));
    return *reinterpret_cast<unsigned*>(&h);
}

// ---- kernel 0: prepack SCL*W2^T into bf16 MFMA A-fragment order (r8 layout) ----
// lane l of chunk (mt,kstep) holds A[mt*32+(l&31)][kstep*16+(l>>5)*8+i],
// stored at wsA[((mt*16 + kstep)*64 + l)*8 + i]
__global__ void prepack_w2t(const float* __restrict__ W2, unsigned short* __restrict__ wsA) {
    const int k = blockIdx.x;
    const int j = threadIdx.x;
    const unsigned short b = f2bf(SCL * W2[k * HD + j]);
    const int kstep = k >> 4, kl = k & 15, hi2 = kl >> 3, i = kl & 7;
    const int mt = j >> 5, jl = j & 31;
    wsA[(((mt * 16) + kstep) * 64 + (hi2 * 32 + jl)) * 8 + i] = b;
}

// ---- kernel 1: tabulate dz = f(te,z), dd = df/dz(te,z) on the z-grid ----
// 450 blocks = 9 te x 50 chunks of 32 grid points; 512 threads; r8 MFMA engine.
__global__ __launch_bounds__(512, 4)
void build_table(const float* __restrict__ W1,
                 const float* __restrict__ b1,
                 const float* __restrict__ b2,
                 const float* __restrict__ W3,
                 const float* __restrict__ b3,
                 const unsigned short* __restrict__ wsA,
                 float2* __restrict__ tbl)
{
    __shared__ __align__(16) short Abuf[64 * 256];            // 32 KB
    __shared__ float w1zS[HD], w1tS[HD], b1S[HD], w0S[HD];    // 4 KB
    __shared__ float b2sc[HD], w3t[HD];                       // 2 KB
    __shared__ float2 kz[8][32];                              // 2 KB -> 40,960 B

    const int tid  = threadIdx.x;
    const int lane = tid & 63;
    const int c    = lane & 31;
    const int hi   = lane >> 5;
    const int wid  = tid >> 6;        // wave: j in [wid*32, wid*32+32)
    const int s    = tid & 31;        // grid point within chunk
    const int fb   = tid >> 5;        // staging feature block 0..15
    const int teI  = blockIdx.x / (G / 32);
    const int zblk = blockIdx.x % (G / 32);

    const float te = teI * 0.125f;
    const float zv = ZMIN + (float)(zblk * 32 + s) * HSTEP;

    if (tid < HD) {
        const float w0 = W1[tid];
        w1zS[tid] = SCL * w0;
        w1tS[tid] = SCL * W1[HD + tid];
        b1S[tid]  = SCL * b1[tid];
        w0S[tid]  = w0;
        b2sc[tid] = SCL * b2[tid];
        w3t[tid]  = W3[tid];
    }
    const float b3v = b3[0];

    // coalesced fragment load: 16 x dwordx4 per lane (replaces 128 scalar loads)
    const short8* __restrict__ wsA8 = (const short8*)wsA;
    short8 w2f[16];
    #pragma unroll
    for (int kk = 0; kk < 16; ++kk)
        w2f[kk] = wsA8[(wid * 16 + kk) * 64 + lane];
    __syncthreads();

    const f32x2 one2 = {1.f, 1.f};
    const f32x2 m2   = {-2.f, -2.f};
    uint4* __restrict__ Ab4 = (uint4*)Abuf;
    const short8* __restrict__ Ab8 = (const short8*)Abuf;
    const int jb = wid * 32 + hi * 4;

    // ---- phase 1: h1/th1 for the 32 grid points (r8 verbatim) ----
    {
        const f32x2 zc2 = {zv, zv};
        const f32x2 te2 = {te, te};
        #pragma unroll
        for (int g2 = 0; g2 < 2; ++g2) {
            const int j0 = fb * 16 + g2 * 8;
            const float4 wzA = *(const float4*)&w1zS[j0];
            const float4 wzB = *(const float4*)&w1zS[j0 + 4];
            const float4 wtA = *(const float4*)&w1tS[j0];
            const float4 wtB = *(const float4*)&w1tS[j0 + 4];
            const float4 bbA = *(const float4*)&b1S[j0];
            const float4 bbB = *(const float4*)&b1S[j0 + 4];
            const float4 w0A = *(const float4*)&w0S[j0];
            const float4 w0B = *(const float4*)&w0S[j0 + 4];
            const f32x2 wz[4]  = {{wzA.x, wzA.y}, {wzA.z, wzA.w}, {wzB.x, wzB.y}, {wzB.z, wzB.w}};
            const f32x2 wt[4]  = {{wtA.x, wtA.y}, {wtA.z, wtA.w}, {wtB.x, wtB.y}, {wtB.z, wtB.w}};
            const f32x2 bb[4]  = {{bbA.x, bbA.y}, {bbA.z, bbA.w}, {bbB.x, bbB.y}, {bbB.z, bbB.w}};
            const f32x2 w0p[4] = {{w0A.x, w0A.y}, {w0A.z, w0A.w}, {w0B.x, w0B.y}, {w0B.z, w0B.w}};
            f32x2 hh[4], th[4];
            #pragma unroll
            for (int pp = 0; pp < 4; ++pp) {
                const f32x2 a = __builtin_elementwise_fma(zc2, wz[pp],
                                  __builtin_elementwise_fma(te2, wt[pp], bb[pp]));
                f32x2 ev; ev.x = __builtin_amdgcn_exp2f(a.x);
                          ev.y = __builtin_amdgcn_exp2f(a.y);
                const f32x2 e1 = ev + one2;
                f32x2 rv; rv.x = __builtin_amdgcn_rcpf(e1.x);
                          rv.y = __builtin_amdgcn_rcpf(e1.y);
                const f32x2 h  = __builtin_elementwise_fma(m2, rv, one2);   // tanh
                const f32x2 t1 = __builtin_elementwise_fma(-h, h, one2);    // 1 - h^2
                hh[pp] = h;
                th[pp] = t1 * w0p[pp];
            }
            uint4 vU, vT;
            vU.x = pk2(hh[0].x, hh[0].y);  vU.y = pk2(hh[1].x, hh[1].y);
            vU.z = pk2(hh[2].x, hh[2].y);  vU.w = pk2(hh[3].x, hh[3].y);
            vT.x = pk2(th[0].x, th[0].y);  vT.y = pk2(th[1].x, th[1].y);
            vT.z = pk2(th[2].x, th[2].y);  vT.w = pk2(th[3].x, th[3].y);
            const int gr = j0 >> 3;
            Ab4[gr * 64 + s]      = vU;
            Ab4[gr * 64 + 32 + s] = vT;
        }
    }
    __syncthreads();

    // ---- phase 2: MFMA (r8 verbatim) ----
    f32x16 accU, accT;
    #pragma unroll
    for (int rq = 0; rq < 4; ++rq) {
        const float4 bq = *(const float4*)&b2sc[jb + rq * 8];
        accU[rq * 4 + 0] = bq.x;  accU[rq * 4 + 1] = bq.y;
        accU[rq * 4 + 2] = bq.z;  accU[rq * 4 + 3] = bq.w;
        accT[rq * 4 + 0] = 0.f;   accT[rq * 4 + 1] = 0.f;
        accT[rq * 4 + 2] = 0.f;   accT[rq * 4 + 3] = 0.f;
    }
    #pragma unroll
    for (int kk = 0; kk < 16; ++kk) {
        const short8 hU = Ab8[(kk * 2 + hi) * 64 + c];
        const short8 hT = Ab8[(kk * 2 + hi) * 64 + 32 + c];
        accU = __builtin_amdgcn_mfma_f32_32x32x16_bf16(w2f[kk], hU, accU, 0, 0, 0);
        accT = __builtin_amdgcn_mfma_f32_32x32x16_bf16(w2f[kk], hT, accT, 0, 0, 0);
    }

    // ---- phase 3: epilogue (r8 verbatim) ----
    f32x2 pz2 = {0.f, 0.f}, pd2 = {0.f, 0.f};
    #pragma unroll
    for (int rq = 0; rq < 4; ++rq) {
        const float4 w3q = *(const float4*)&w3t[jb + rq * 8];
        const f32x2 w3p[2] = {{w3q.x, w3q.y}, {w3q.z, w3q.w}};
        #pragma unroll
        for (int pr = 0; pr < 2; ++pr) {
            const int r = rq * 4 + pr * 2;
            const f32x2 u2 = {accU[r], accU[r + 1]};
            const f32x2 t2 = {accT[r], accT[r + 1]};
            f32x2 ev; ev.x = __builtin_amdgcn_exp2f(u2.x);
                      ev.y = __builtin_amdgcn_exp2f(u2.y);
            const f32x2 e1 = ev + one2;
            f32x2 rv; rv.x = __builtin_amdgcn_rcpf(e1.x);
                      rv.y = __builtin_amdgcn_rcpf(e1.y);
            const f32x2 h2 = __builtin_elementwise_fma(m2, rv, one2);
            const f32x2 hq = h2 * h2;
            const f32x2 th2 = __builtin_elementwise_fma(-hq, t2, t2);
            pz2 = __builtin_elementwise_fma(h2,  w3p[pr], pz2);
            pd2 = __builtin_elementwise_fma(th2, w3p[pr], pd2);
        }
    }
    float pdz = pz2.x + pz2.y;
    float pdd = (pd2.x + pd2.y) * SCLINV;
    pdz += __shfl_xor(pdz, 32);
    pdd += __shfl_xor(pdd, 32);
    if (hi == 0) kz[wid][c] = make_float2(pdz, pdd);
    __syncthreads();

    if (tid < 32) {
        float kzs = b3v, kds = 0.f;
        #pragma unroll
        for (int w = 0; w < 8; ++w) {
            const float2 a = kz[w][tid];
            kzs += a.x; kds += a.y;
        }
        tbl[teI * G + zblk * 32 + tid] = make_float2(kzs, kds);
    }
}

// ---- kernel 2: RK4 integration of all samples via table interpolation ----
__global__ __launch_bounds__(256)
void integrate(const float* __restrict__ z0,
               const float2* __restrict__ tbl,
               float* __restrict__ out)
{
    __shared__ float2 sl[G];                 // 12.8 KB: current te slice
    const int tid = threadIdx.x;
    const int sid = blockIdx.x * 256 + tid;

    float zb = z0[sid];
    float zc = zb, skz = 0.f, skd = 0.f, dacc = 0.f;
    const float dt = 0.25f;
    int prev = -1;

    for (int it = 0; it < 16; ++it) {
        const int st = it >> 2, e = it & 3;
        const int idx = 2 * st + ((e == 0) ? 0 : (e == 3) ? 2 : 1);
        if (idx != prev) {                    // block-uniform condition
            __syncthreads();
            for (int g = tid; g < G; g += 256)
                sl[g] = tbl[idx * G + g];
            __syncthreads();
            prev = idx;
        }
        float xf = (zc - ZMIN) * INVH;
        xf = fminf(fmaxf(xf, 0.0f), (float)(G - 1));
        int i0 = (int)xf;
        if (i0 > G - 2) i0 = G - 2;
        const float w  = xf - (float)i0;
        const float2 a = sl[i0];
        const float2 b = sl[i0 + 1];
        const float kzv = fmaf(w, b.x - a.x, a.x);
        const float kdv = fmaf(w, b.y - a.y, a.y);

        const float cw = (e == 1 || e == 2) ? 2.f : 1.f;
        skz += cw * kzv;
        skd += cw * kdv;
        if (e < 3) {
            zc = fmaf((e == 2) ? dt : 0.5f * dt, kzv, zb);
        } else {
            zb   = fmaf(dt / 6.f, skz, zb);
            zc   = zb;
            dacc = fmaf(dt / 6.f, skd, dacc);
            skz = 0.f; skd = 0.f;
        }
    }

    out[sid]         = zb;      // zf
    out[BATCH + sid] = dacc;    // div_int
}

extern "C" void kernel_launch(void* const* d_in, const int* in_sizes, int n_in,
                              void* d_out, int out_size, void* d_ws, size_t ws_size,
                              hipStream_t stream) {
    const float* z0 = (const float*)d_in[0];
    const float* W1 = (const float*)d_in[1];
    const float* b1 = (const float*)d_in[2];
    const float* W2 = (const float*)d_in[3];
    const float* b2 = (const float*)d_in[4];
    const float* W3 = (const float*)d_in[5];
    const float* b3 = (const float*)d_in[6];
    float* out = (float*)d_out;

    float2* tbl = (float2*)d_ws;                                   // 115,200 B
    unsigned short* wsA = (unsigned short*)((char*)d_ws + 131072); // 128 KB frag W2^T

    hipLaunchKernelGGL(prepack_w2t, dim3(HD), dim3(HD), 0, stream, W2, wsA);
    hipLaunchKernelGGL(build_table, dim3(NTE * (G / 32)), dim3(512), 0, stream,
                       W1, b1, b2, W3, b3, wsA, tbl);
    hipLaunchKernelGGL(integrate, dim3(BATCH / 256), dim3(256), 0, stream,
                       z0, tbl, out);
}